// Round 4
// baseline (202.030 us; speedup 1.0000x reference)
//
#include <hip/hip_runtime.h>
#include <math.h>

// Problem constants
#define VDIM   128
#define KCODES 512
#define NROWS  (32 * 4096)      // 131072
#define TILE_ROWS 128           // rows per block (4 waves x 32 rows)
#define TN 0.67882250993908565f // 0.06 * sqrt(128)

typedef __attribute__((ext_vector_type(8))) short bf16x8;  // MFMA A/B frag (4 VGPR)
typedef __attribute__((ext_vector_type(4))) float f32x4;   // MFMA C/D frag

__device__ __forceinline__ unsigned short f2bf(float f) {
    unsigned u = __float_as_uint(f);
    unsigned r = u + 0x7FFFu + ((u >> 16) & 1u);   // round-to-nearest-even
    return (unsigned short)(r >> 16);
}

__device__ __forceinline__ bf16x8 pack8(float4 a, float4 b) {
    bf16x8 v;
    v[0] = (short)f2bf(a.x); v[1] = (short)f2bf(a.y);
    v[2] = (short)f2bf(a.z); v[3] = (short)f2bf(a.w);
    v[4] = (short)f2bf(b.x); v[5] = (short)f2bf(b.y);
    v[6] = (short)f2bf(b.z); v[7] = (short)f2bf(b.w);
    return v;
}

// Normalize codes: embn fp32 (for out0 gather), ebf bf16 (MFMA B), e2 = ||e||^2
__global__ void prep_emb(const float* __restrict__ emb0,
                         float* __restrict__ embn,
                         unsigned short* __restrict__ ebf,
                         float* __restrict__ e2) {
    int k = blockIdx.x;       // KCODES blocks
    int l = threadIdx.x;      // 64 threads = 1 wave
    const float* row = emb0 + (size_t)k * VDIM;
    float a = row[l];
    float b = row[l + 64];
    float ss = a * a + b * b;
    #pragma unroll
    for (int off = 32; off; off >>= 1) ss += __shfl_xor(ss, off);
    float nrm = sqrtf(ss);
    float ea = (TN * a) / nrm;
    float eb = (TN * b) / nrm;
    embn[(size_t)k * VDIM + l]      = ea;
    embn[(size_t)k * VDIM + l + 64] = eb;
    ebf[(size_t)k * VDIM + l]      = f2bf(ea);
    ebf[(size_t)k * VDIM + l + 64] = f2bf(eb);
    float s2 = ea * ea + eb * eb;
    #pragma unroll
    for (int off = 32; off; off >>= 1) s2 += __shfl_xor(s2, off);
    if (l == 0) e2[k] = s2;
}

// Main: per wave, 2 row-strips of 16 (A frags in VGPRs, ~32 VGPR); scan 512
// codes via bf16 MFMA, B frags ping-pong double-buffered from L2.
// argmin(dist) == argmax(dot(x0, e)) since ||x|| and ||e|| are constant.
__global__ __launch_bounds__(256, 4) void vq_main(
        const float* __restrict__ x0,
        const unsigned short* __restrict__ ebf,
        const float* __restrict__ embn,
        const float* __restrict__ e2,
        unsigned* __restrict__ hist,
        float* __restrict__ out0,
        float* __restrict__ out1,
        float* __restrict__ out2) {
    int t = threadIdx.x;
    int w = t >> 6;           // wave 0..3
    int l = t & 63;
    int n15 = l & 15;         // MFMA m (A rows), n (B cols), col (C)
    int q = l >> 4;           // quad: input k = q*8 + j; C row = q*4 + r

    // ---- Load A: 2 strips x 16 rows, K=128 as 4 k-chunks; fp32 -> bf16 frags
    int rowbase = blockIdx.x * TILE_ROWS + (w << 5);
    bf16x8 afr[2][4];
    float nsq[2];
    #pragma unroll
    for (int s = 0; s < 2; ++s) {
        const float* xrow = x0 + (size_t)(rowbase + (s << 4) + n15) * VDIM + (q << 3);
        float p0 = 0.f, p1 = 0.f;
        #pragma unroll
        for (int kc = 0; kc < 4; ++kc) {
            const float4* xp = (const float4*)(xrow + (kc << 5));
            float4 a = xp[0], b = xp[1];
            p0 = fmaf(a.x, a.x, p0); p1 = fmaf(a.y, a.y, p1);
            p0 = fmaf(a.z, a.z, p0); p1 = fmaf(a.w, a.w, p1);
            p0 = fmaf(b.x, b.x, p0); p1 = fmaf(b.y, b.y, p1);
            p0 = fmaf(b.z, b.z, p0); p1 = fmaf(b.w, b.w, p1);
            afr[s][kc] = pack8(a, b);
        }
        nsq[s] = p0 + p1;
        nsq[s] += __shfl_xor(nsq[s], 16, 64);   // reduce ||x0||^2 across quads
        nsq[s] += __shfl_xor(nsq[s], 32, 64);
    }

    // ---- N-loop: 32 chunks of 16 codes, ping-pong B prefetch
    float best[2][4];
    int   bidx[2][4];
    #pragma unroll
    for (int s = 0; s < 2; ++s)
        #pragma unroll
        for (int r = 0; r < 4; ++r) { best[s][r] = -3.4e38f; bidx[s][r] = 0; }

    const f32x4 zero4 = {0.f, 0.f, 0.f, 0.f};
    const bf16x8* eb8 = (const bf16x8*)ebf;   // code row = 16 frag slots
    const bf16x8* bp0 = eb8 + (size_t)n15 * 16 + q;

    bf16x8 ba[4], bb[4];
    ba[0] = bp0[0]; ba[1] = bp0[4]; ba[2] = bp0[8]; ba[3] = bp0[12];

#define PROCESS(BUF, CN)                                                        \
    do {                                                                        \
        int n_ = ((CN) << 4) | n15;                                             \
        _Pragma("unroll")                                                       \
        for (int s = 0; s < 2; ++s) {                                           \
            f32x4 acc = __builtin_amdgcn_mfma_f32_16x16x32_bf16(                \
                afr[s][0], BUF[0], zero4, 0, 0, 0);                             \
            acc = __builtin_amdgcn_mfma_f32_16x16x32_bf16(                      \
                afr[s][1], BUF[1], acc, 0, 0, 0);                               \
            acc = __builtin_amdgcn_mfma_f32_16x16x32_bf16(                      \
                afr[s][2], BUF[2], acc, 0, 0, 0);                               \
            acc = __builtin_amdgcn_mfma_f32_16x16x32_bf16(                      \
                afr[s][3], BUF[3], acc, 0, 0, 0);                               \
            _Pragma("unroll")                                                   \
            for (int r = 0; r < 4; ++r) {                                       \
                float d = acc[r];                                               \
                if (d > best[s][r]) { best[s][r] = d; bidx[s][r] = n_; }        \
            }                                                                   \
        }                                                                       \
    } while (0)

    for (int cn = 0; cn < 32; cn += 2) {
        // prefetch chunk cn+1 into bb while computing ba
        {
            const bf16x8* bp = eb8 + ((size_t)(((cn + 1) << 4) | n15)) * 16 + q;
            bb[0] = bp[0]; bb[1] = bp[4]; bb[2] = bp[8]; bb[3] = bp[12];
        }
        PROCESS(ba, cn);
        // prefetch chunk cn+2 into ba (clamped at the tail) while computing bb
        {
            int cnn = cn + 2 < 32 ? cn + 2 : 31;
            const bf16x8* bp = eb8 + ((size_t)((cnn << 4) | n15)) * 16 + q;
            ba[0] = bp[0]; ba[1] = bp[4]; ba[2] = bp[8]; ba[3] = bp[12];
        }
        PROCESS(bb, cn + 1);
    }
#undef PROCESS

    // ---- Reduce argmax across the 16 lanes (C cols) holding the same row
    #pragma unroll
    for (int m = 1; m <= 8; m <<= 1) {
        #pragma unroll
        for (int s = 0; s < 2; ++s)
            #pragma unroll
            for (int r = 0; r < 4; ++r) {
                float ov = __shfl_xor(best[s][r], m, 64);
                int   oi = __shfl_xor(bidx[s][r], m, 64);
                if (ov > best[s][r] || (ov == best[s][r] && oi < bidx[s][r])) {
                    best[s][r] = ov; bidx[s][r] = oi;
                }
            }
    }

    // ---- Stage per-row results to LDS for the coalesced epilogue
    __shared__ int   sbesti[TILE_ROWS];
    __shared__ float sdot[TILE_ROWS];
    __shared__ float sn0[TILE_ROWS];
    if (n15 == 0) {
        #pragma unroll
        for (int s = 0; s < 2; ++s)
            #pragma unroll
            for (int r = 0; r < 4; ++r) {
                int lr = (w << 5) + (s << 4) + (q << 2) + r;  // C row = q*4+r
                sbesti[lr] = bidx[s][r];
                sdot[lr]   = best[s][r];
            }
    }
    if (q == 0) {
        #pragma unroll
        for (int s = 0; s < 2; ++s) sn0[(w << 5) + (s << 4) + n15] = nsq[s];
    }
    __syncthreads();

    // ---- Epilogue A: coalesced out0 copy (32 lanes cover one row's 512 B)
    size_t blockrow = (size_t)blockIdx.x * TILE_ROWS;
    #pragma unroll
    for (int pass = 0; pass < 16; ++pass) {
        int lr = (pass << 3) + (t >> 5);   // 8 rows per pass
        int v4 = t & 31;                   // float4 slot within the row
        int bi = sbesti[lr];
        float4 e = ((const float4*)(embn + (size_t)bi * VDIM))[v4];
        ((float4*)(out0 + (blockrow + lr) * (size_t)VDIM))[v4] = e;
    }

    // ---- Epilogue B: per-row scalars (threads 0..127)
    if (t < TILE_ROWS) {
        size_t row = blockrow + t;
        int bi = sbesti[t];
        float dotv = sdot[t];
        float nn = sn0[t];
        float sc = TN / sqrtf(nn);                      // x = sc * x0
        float o1 = TN * TN + e2[bi] - 2.f * sc * dotv;  // sum (x-e)^2
        out1[row] = o1;
        float sm = sc - 1.f;
        out2[row] = o1 + sm * sm * nn;                  // + sum (x-x0)^2
        atomicAdd(&hist[bi], 1u);
    }
}

__global__ void entropy_k(const unsigned* __restrict__ hist,
                          float* __restrict__ out) {
    __shared__ float red[8];
    int t = threadIdx.x;   // KCODES threads
    float h = (float)hist[t];
    float p = h / (float)NROWS;
    float term = (h > 0.f) ? p * logf(p) : 0.f;
    #pragma unroll
    for (int off = 32; off; off >>= 1) term += __shfl_xor(term, off);
    if ((t & 63) == 0) red[t >> 6] = term;
    __syncthreads();
    if (t == 0) {
        float ssum = 0.f;
        #pragma unroll
        for (int i = 0; i < 8; i++) ssum += red[i];
        out[0] = -ssum;
    }
}

extern "C" void kernel_launch(void* const* d_in, const int* in_sizes, int n_in,
                              void* d_out, int out_size, void* d_ws, size_t ws_size,
                              hipStream_t stream) {
    const float* x0   = (const float*)d_in[0];
    const float* emb0 = (const float*)d_in[1];

    float* embn = (float*)d_ws;                              // 512*128 f32 = 256 KB
    float* e2   = embn + (size_t)KCODES * VDIM;              // 512 f32
    unsigned* hist = (unsigned*)(e2 + KCODES);               // 512 u32
    unsigned short* ebf = (unsigned short*)(hist + KCODES);  // 512*128 bf16 = 128 KB

    float* out  = (float*)d_out;
    float* out0 = out;
    float* out1 = out0 + (size_t)NROWS * VDIM;
    float* out2 = out1 + NROWS;
    float* oent = out2 + NROWS;

    hipMemsetAsync(hist, 0, KCODES * sizeof(unsigned), stream);
    prep_emb<<<KCODES, 64, 0, stream>>>(emb0, embn, ebf, e2);
    vq_main<<<NROWS / TILE_ROWS, 256, 0, stream>>>(x0, ebf, embn, e2, hist,
                                                   out0, out1, out2);
    entropy_k<<<1, KCODES, 0, stream>>>(hist, oent);
}

// Round 5
// 166.099 us; speedup vs baseline: 1.2163x; 1.2163x over previous
//
#include <hip/hip_runtime.h>
#include <math.h>

// Problem constants
#define VDIM   128
#define KCODES 512
#define NROWS  (32 * 4096)      // 131072
#define TILE_ROWS 128           // rows per block (4 waves x 32 rows)
#define STAGE_CODES 128         // codes staged in LDS per stage (32 KB)
#define STAGE_GRAN (STAGE_CODES * 16)   // 16B granules per stage
#define TN 0.67882250993908565f // 0.06 * sqrt(128)

typedef __attribute__((ext_vector_type(8))) short bf16x8;  // MFMA A/B frag (4 VGPR)
typedef __attribute__((ext_vector_type(4))) float f32x4;   // MFMA C/D frag

__device__ __forceinline__ unsigned short f2bf(float f) {
    unsigned u = __float_as_uint(f);
    unsigned r = u + 0x7FFFu + ((u >> 16) & 1u);   // round-to-nearest-even
    return (unsigned short)(r >> 16);
}

__device__ __forceinline__ bf16x8 pack8(float4 a, float4 b) {
    bf16x8 v;
    v[0] = (short)f2bf(a.x); v[1] = (short)f2bf(a.y);
    v[2] = (short)f2bf(a.z); v[3] = (short)f2bf(a.w);
    v[4] = (short)f2bf(b.x); v[5] = (short)f2bf(b.y);
    v[6] = (short)f2bf(b.z); v[7] = (short)f2bf(b.w);
    return v;
}

// Normalize codes: embn fp32 (for out0 gather), ebf bf16 (MFMA B table)
__global__ void prep_emb(const float* __restrict__ emb0,
                         float* __restrict__ embn,
                         unsigned short* __restrict__ ebf) {
    int k = blockIdx.x;       // KCODES blocks
    int l = threadIdx.x;      // 64 threads = 1 wave
    const float* row = emb0 + (size_t)k * VDIM;
    float a = row[l];
    float b = row[l + 64];
    float ss = a * a + b * b;
    #pragma unroll
    for (int off = 32; off; off >>= 1) ss += __shfl_xor(ss, off);
    float nrm = sqrtf(ss);
    float ea = (TN * a) / nrm;
    float eb = (TN * b) / nrm;
    embn[(size_t)k * VDIM + l]      = ea;
    embn[(size_t)k * VDIM + l + 64] = eb;
    ebf[(size_t)k * VDIM + l]      = f2bf(ea);
    ebf[(size_t)k * VDIM + l + 64] = f2bf(eb);
}

// Main: 4 waves x 32 rows. A frags resident in VGPRs; B code table staged
// through LDS in 4 x 32KB stages, fragments stored lane-linear so both
// ds_write_b128 and ds_read_b128 are stride-1 (conflict-free, no padding).
// argmin(dist) == argmax(dot(x0,e)) since ||x|| = ||e|| = tn exactly.
__global__ __launch_bounds__(256, 4) void vq_main(
        const float* __restrict__ x0,
        const unsigned short* __restrict__ ebf,
        const float* __restrict__ embn,
        unsigned* __restrict__ hist,
        float* __restrict__ out0,
        float* __restrict__ out1,
        float* __restrict__ out2) {
    __shared__ uint4 sB[STAGE_GRAN];        // 32 KB staged B fragments
    __shared__ int   sbesti[TILE_ROWS];
    __shared__ float sdot[TILE_ROWS];
    __shared__ float sn0[TILE_ROWS];

    int t = threadIdx.x;
    int w = t >> 6;           // wave 0..3
    int l = t & 63;
    int n15 = l & 15;         // MFMA m (A rows), n (B cols), col (C)
    int q = l >> 4;           // quad: input k = q*8 + j; C row = q*4 + r

    // ---- Load A: 2 strips x 16 rows, K=128 as 4 k-chunks; fp32 -> bf16 frags
    int rowbase = blockIdx.x * TILE_ROWS + (w << 5);
    bf16x8 afr[2][4];
    float nsq[2];
    #pragma unroll
    for (int s = 0; s < 2; ++s) {
        const float* xrow = x0 + (size_t)(rowbase + (s << 4) + n15) * VDIM + (q << 3);
        float p0 = 0.f, p1 = 0.f;
        #pragma unroll
        for (int kc = 0; kc < 4; ++kc) {
            const float4* xp = (const float4*)(xrow + (kc << 5));
            float4 a = xp[0], b = xp[1];
            p0 = fmaf(a.x, a.x, p0); p1 = fmaf(a.y, a.y, p1);
            p0 = fmaf(a.z, a.z, p0); p1 = fmaf(a.w, a.w, p1);
            p0 = fmaf(b.x, b.x, p0); p1 = fmaf(b.y, b.y, p1);
            p0 = fmaf(b.z, b.z, p0); p1 = fmaf(b.w, b.w, p1);
            afr[s][kc] = pack8(a, b);
        }
        nsq[s] = p0 + p1;
        nsq[s] += __shfl_xor(nsq[s], 16, 64);   // reduce ||x0||^2 across quads
        nsq[s] += __shfl_xor(nsq[s], 32, 64);
    }

    float best[2][4];
    int   bidx[2][4];
    #pragma unroll
    for (int s = 0; s < 2; ++s)
        #pragma unroll
        for (int r = 0; r < 4; ++r) { best[s][r] = -3.4e38f; bidx[s][r] = 0; }

    const f32x4 zero4 = {0.f, 0.f, 0.f, 0.f};
    const uint4* ebg = (const uint4*)ebf;       // 16B-granule view of code table

    // ---- 4 stages of 128 codes each
    for (int st = 0; st < 4; ++st) {
        if (st) __syncthreads();                // previous stage fully consumed

        // Stage: LDS granule lid = r*256 + t (stride-1 ds_write_b128).
        // Decode lid -> (chunk cn8=r, kc=t>>6, q=(t>>4)&3, n=t&15); fetch the
        // matching global granule (16 x 64B segments per wave instruction).
        #pragma unroll
        for (int r = 0; r < 8; ++r) {
            int code = st * STAGE_CODES + (r << 4) + (t & 15);
            int gran = ((t >> 6) << 2) + ((t >> 4) & 3);
            sB[(r << 8) + t] = ebg[(size_t)code * 16 + gran];
        }
        __syncthreads();

        // 8 chunks of 16 codes from LDS (lane-linear frags: stride-1 reads)
        #pragma unroll 2
        for (int cn8 = 0; cn8 < 8; ++cn8) {
            const bf16x8* bls = ((const bf16x8*)sB) + (cn8 << 8) + l;
            bf16x8 b0 = bls[0], b1 = bls[64], b2 = bls[128], b3 = bls[192];
            int nbase = st * STAGE_CODES + (cn8 << 4) + n15;
            #pragma unroll
            for (int s = 0; s < 2; ++s) {
                f32x4 acc = __builtin_amdgcn_mfma_f32_16x16x32_bf16(afr[s][0], b0, zero4, 0, 0, 0);
                acc = __builtin_amdgcn_mfma_f32_16x16x32_bf16(afr[s][1], b1, acc, 0, 0, 0);
                acc = __builtin_amdgcn_mfma_f32_16x16x32_bf16(afr[s][2], b2, acc, 0, 0, 0);
                acc = __builtin_amdgcn_mfma_f32_16x16x32_bf16(afr[s][3], b3, acc, 0, 0, 0);
                #pragma unroll
                for (int r = 0; r < 4; ++r) {
                    float d = acc[r];
                    if (d > best[s][r]) { best[s][r] = d; bidx[s][r] = nbase; }
                }
            }
        }
    }

    // ---- Reduce argmax across the 16 lanes (C cols) holding the same row
    #pragma unroll
    for (int m = 1; m <= 8; m <<= 1) {
        #pragma unroll
        for (int s = 0; s < 2; ++s)
            #pragma unroll
            for (int r = 0; r < 4; ++r) {
                float ov = __shfl_xor(best[s][r], m, 64);
                int   oi = __shfl_xor(bidx[s][r], m, 64);
                if (ov > best[s][r] || (ov == best[s][r] && oi < bidx[s][r])) {
                    best[s][r] = ov; bidx[s][r] = oi;
                }
            }
    }

    // ---- Stage per-row results to LDS for the coalesced epilogue
    if (n15 == 0) {
        #pragma unroll
        for (int s = 0; s < 2; ++s)
            #pragma unroll
            for (int r = 0; r < 4; ++r) {
                int lr = (w << 5) + (s << 4) + (q << 2) + r;  // C row = q*4+r
                sbesti[lr] = bidx[s][r];
                sdot[lr]   = best[s][r];
            }
    }
    if (q == 0) {
        #pragma unroll
        for (int s = 0; s < 2; ++s) sn0[(w << 5) + (s << 4) + n15] = nsq[s];
    }
    __syncthreads();

    // ---- Epilogue A: coalesced out0 copy (32 lanes cover one row's 512 B)
    size_t blockrow = (size_t)blockIdx.x * TILE_ROWS;
    #pragma unroll
    for (int pass = 0; pass < 16; ++pass) {
        int lr = (pass << 3) + (t >> 5);   // 8 rows per pass
        int v4 = t & 31;                   // float4 slot within the row
        int bi = sbesti[lr];
        float4 e = ((const float4*)(embn + (size_t)bi * VDIM))[v4];
        ((float4*)(out0 + (blockrow + lr) * (size_t)VDIM))[v4] = e;
    }

    // ---- Epilogue B: per-row scalars (threads 0..127)
    if (t < TILE_ROWS) {
        size_t row = blockrow + t;
        int bi = sbesti[t];
        float dotv = sdot[t];
        float nn = sn0[t];
        float sc = TN / sqrtf(nn);                      // x = sc * x0
        float o1 = 2.f * TN * TN - 2.f * sc * dotv;     // ||x||^2=||e||^2=tn^2
        out1[row] = o1;
        float sm = sc - 1.f;
        out2[row] = o1 + sm * sm * nn;                  // + sum (x-x0)^2
        atomicAdd(&hist[bi], 1u);
    }
}

__global__ void entropy_k(const unsigned* __restrict__ hist,
                          float* __restrict__ out) {
    __shared__ float red[8];
    int t = threadIdx.x;   // KCODES threads
    float h = (float)hist[t];
    float p = h / (float)NROWS;
    float term = (h > 0.f) ? p * logf(p) : 0.f;
    #pragma unroll
    for (int off = 32; off; off >>= 1) term += __shfl_xor(term, off);
    if ((t & 63) == 0) red[t >> 6] = term;
    __syncthreads();
    if (t == 0) {
        float ssum = 0.f;
        #pragma unroll
        for (int i = 0; i < 8; i++) ssum += red[i];
        out[0] = -ssum;
    }
}

extern "C" void kernel_launch(void* const* d_in, const int* in_sizes, int n_in,
                              void* d_out, int out_size, void* d_ws, size_t ws_size,
                              hipStream_t stream) {
    const float* x0   = (const float*)d_in[0];
    const float* emb0 = (const float*)d_in[1];

    float* embn = (float*)d_ws;                              // 512*128 f32 = 256 KB
    unsigned* hist = (unsigned*)(embn + (size_t)KCODES * VDIM); // 512 u32
    unsigned short* ebf = (unsigned short*)(hist + KCODES);  // 512*128 bf16 = 128 KB

    float* out  = (float*)d_out;
    float* out0 = out;
    float* out1 = out0 + (size_t)NROWS * VDIM;
    float* out2 = out1 + NROWS;
    float* oent = out2 + NROWS;

    hipMemsetAsync(hist, 0, KCODES * sizeof(unsigned), stream);
    prep_emb<<<KCODES, 64, 0, stream>>>(emb0, embn, ebf);
    vq_main<<<NROWS / TILE_ROWS, 256, 0, stream>>>(x0, ebf, embn, hist,
                                                   out0, out1, out2);
    entropy_k<<<1, KCODES, 0, stream>>>(hist, oent);
}